// Round 5
// baseline (374.359 us; speedup 1.0000x reference)
//
#include <hip/hip_runtime.h>
#include <stdint.h>

typedef __attribute__((ext_vector_type(8))) short short8;
typedef __attribute__((ext_vector_type(4))) float floatx4;

#define EPS 1e-8f
#define TAU 0.1f
#define LROW 260        // dwords per LDS row: 256 data + 4 pad -> 2-way banks (free)
#define TILES_PER_BLK 8 // 8 tiles x 32 rows = 256 rows per block

// float -> bf16 bits, round-to-nearest-even (prep kernel only)
__device__ __forceinline__ unsigned short f2bf(float f) {
  union { float f; unsigned u; } v; v.f = f;
  unsigned u = v.u;
  u += 0x7fffu + ((u >> 16) & 1u);
  return (unsigned short)(u >> 16);
}

// pack two f32 -> {bf16(hi), bf16(lo)} by truncation: one v_perm_b32
__device__ __forceinline__ unsigned pack2_trunc(float lo, float hi) {
  union { float f; unsigned u; } a, b; a.f = lo; b.f = hi;
  return __builtin_amdgcn_perm(b.u, a.u, 0x07060302u);
}

// async global->LDS DMA, 16B/lane: lane i reads g + i*16, lands at l + i*16
__device__ __forceinline__ void async_copy16(const void* g, void* l) {
  __builtin_amdgcn_global_load_lds(
      (__attribute__((address_space(1))) void*)g,
      (__attribute__((address_space(3))) void*)l, 16, 0, 0);
}

// Kernel 1: normalize prototypes (K=64 x D=256) -> bf16 row-major in ws.
__global__ void proto_prep(const float* __restrict__ protos,
                           unsigned short* __restrict__ pbf) {
  const int l = threadIdx.x & 63;
  const int w = threadIdx.x >> 6;
  const int row = blockIdx.x * 4 + w;
  float4 v = reinterpret_cast<const float4*>(protos)[row * 64 + l];
  float ss = v.x * v.x + v.y * v.y + v.z * v.z + v.w * v.w;
#pragma unroll
  for (int d = 1; d < 64; d <<= 1) ss += __shfl_xor(ss, d, 64);
  const float inv = 1.0f / fmaxf(sqrtf(ss), 1e-12f);
  ushort4 o;
  o.x = f2bf(v.x * inv); o.y = f2bf(v.y * inv);
  o.z = f2bf(v.z * inv); o.w = f2bf(v.w * inv);
  reinterpret_cast<ushort4*>(pbf)[row * 64 + l] = o;
}

// Kernel 2: persistent main. Block owns 256 rows = 8 tiles of 32 rows.
// Double-buffered LDS staging via global_load_lds; DMA for tile t+1 issued
// right after the barrier that publishes tile t, so it flies during compute.
// Waves 2x2: mw = row-half (16 rows), nw = proto-half (32 protos).
__global__ __launch_bounds__(256, 2)
void protonce_main(const float* __restrict__ feat,
                   const unsigned short* __restrict__ pbf,
                   const int* __restrict__ labels,
                   float* __restrict__ partials) {
  __shared__ __align__(16) float Abuf[2][32 * LROW];  // 66560 B
  __shared__ float dn_sm[2][2][32];                   // [parity][nw][row]
  __shared__ float nm_sm[2][2][32];

  const int tid = threadIdx.x;
  const int l = tid & 63;
  const int w = tid >> 6;
  const int mw = w & 1;
  const int nw = w >> 1;
  const int n = l & 15;
  const int q = l >> 4;
  const long blockRow0 = (long)blockIdx.x * 256;

  // ---- prologue: B fragments + all labels to registers; DMA tile 0 ----
  const unsigned short* bbase = pbf + (nw * 32 + n) * 256 + q * 8;
  short8 bv[16];
#pragma unroll
  for (int s = 0; s < 8; ++s) {
    bv[2 * s]     = *reinterpret_cast<const short8*>(bbase + s * 32);
    bv[2 * s + 1] = *reinterpret_cast<const short8*>(bbase + 16 * 256 + s * 32);
  }
  int4 lab[TILES_PER_BLK];
#pragma unroll
  for (int t = 0; t < TILES_PER_BLK; ++t)
    lab[t] = *reinterpret_cast<const int4*>(
        labels + blockRow0 + t * 32 + mw * 16 + q * 4);

  const float* srcw = feat + (blockRow0 + w * 8) * 256 + l * 4;  // wave's row w*8, lane offset
#pragma unroll
  for (int j = 0; j < 8; ++j)
    async_copy16(srcw + j * 256, &Abuf[0][(w * 8 + j) * LROW]);

  float lossAcc = 0.f;   // meaningful on wave 0 only

  for (int t = 0; t < TILES_PER_BLK; ++t) {
    const int p = t & 1;
    __syncthreads();     // tile t staged; dn_sm[(t-1)&1] published

    // issue DMA for tile t+1 into the other buffer (flies during compute)
    if (t + 1 < TILES_PER_BLK) {
      const float* s2 = srcw + (long)(t + 1) * 32 * 256;
#pragma unroll
      for (int j = 0; j < 8; ++j)
        async_copy16(s2 + j * 256, &Abuf[p ^ 1][(w * 8 + j) * LROW]);
    }

    // deferred finalize of tile t-1 (wave 0 only; parity slot (t-1)&1)
    if (t > 0 && w == 0 && l < 32) {
      const int pp = (t - 1) & 1;
      const float den = dn_sm[pp][0][l] + dn_sm[pp][1][l];
      const float num = nm_sm[pp][0][l] + nm_sm[pp][1][l];
      lossAcc += -__logf((num + EPS) / (den + EPS) + EPS);
    }

    // ---- compute tile t: ds_read -> norm FMA -> pack -> MFMA ----
    floatx4 acc0 = {0.f, 0.f, 0.f, 0.f}, acc1 = {0.f, 0.f, 0.f, 0.f};
    float ss = 0.f;
    const float* arow = &Abuf[p][(mw * 16 + n) * LROW + q * 8];
#pragma unroll
    for (int s = 0; s < 8; ++s) {
      float4 x = *reinterpret_cast<const float4*>(arow + s * 32);
      float4 y = *reinterpret_cast<const float4*>(arow + s * 32 + 4);
      ss += x.x * x.x + x.y * x.y + x.z * x.z + x.w * x.w +
            y.x * y.x + y.y * y.y + y.z * y.z + y.w * y.w;
      union { short8 s8; uint4 u4; } af;
      af.u4.x = pack2_trunc(x.x, x.y);
      af.u4.y = pack2_trunc(x.z, x.w);
      af.u4.z = pack2_trunc(y.x, y.y);
      af.u4.w = pack2_trunc(y.z, y.w);
      acc0 = __builtin_amdgcn_mfma_f32_16x16x32_bf16(af.s8, bv[2 * s],     acc0, 0, 0, 0);
      acc1 = __builtin_amdgcn_mfma_f32_16x16x32_bf16(af.s8, bv[2 * s + 1], acc1, 0, 0, 0);
    }
    ss += __shfl_xor(ss, 16, 64);
    ss += __shfl_xor(ss, 32, 64);   // every lane: ||f||^2 of row (mw*16 + (l&15))

    const int4 lv = lab[t];
#pragma unroll
    for (int r = 0; r < 4; ++r) {
      const float nrm = __shfl(ss, q * 4 + r, 64);
      const float sc = 1.0f / (fmaxf(sqrtf(nrm), 1e-12f) * TAU);
      const int labv = (r == 0) ? lv.x : (r == 1) ? lv.y : (r == 2) ? lv.z : lv.w;
      const float e0 = __expf(acc0[r] * sc);
      const float e1 = __expf(acc1[r] * sc);
      float den = e0 + e1;
      float num = (nw * 32 + n == labv ? e0 : 0.f) +
                  (nw * 32 + 16 + n == labv ? e1 : 0.f);
#pragma unroll
      for (int d = 1; d < 16; d <<= 1) {
        den += __shfl_xor(den, d, 64);
        num += __shfl_xor(num, d, 64);
      }
      if (n == 0) {
        dn_sm[p][nw][mw * 16 + q * 4 + r] = den;
        nm_sm[p][nw][mw * 16 + q * 4 + r] = num;
      }
    }
  }

  __syncthreads();       // publish last tile's partials
  if (w == 0) {
    if (l < 32) {
      const int pp = (TILES_PER_BLK - 1) & 1;
      const float den = dn_sm[pp][0][l] + dn_sm[pp][1][l];
      const float num = nm_sm[pp][0][l] + nm_sm[pp][1][l];
      lossAcc += -__logf((num + EPS) / (den + EPS) + EPS);
    }
#pragma unroll
    for (int d = 1; d < 64; d <<= 1) lossAcc += __shfl_xor(lossAcc, d, 64);
    if (l == 0) partials[blockIdx.x] = lossAcc;
  }
}

// Kernel 3: deterministic reduce of per-block partials -> mean
__global__ void finalize_k(const float* __restrict__ partials, int nblocks,
                           float* __restrict__ out, float invB) {
  __shared__ float red[256];
  float s = 0.f;
  for (int i = threadIdx.x; i < nblocks; i += 256) s += partials[i];
  red[threadIdx.x] = s;
  __syncthreads();
#pragma unroll
  for (int d = 128; d > 0; d >>= 1) {
    if (threadIdx.x < d) red[threadIdx.x] += red[threadIdx.x + d];
    __syncthreads();
  }
  if (threadIdx.x == 0) out[0] = red[0] * invB;
}

extern "C" void kernel_launch(void* const* d_in, const int* in_sizes, int n_in,
                              void* d_out, int out_size, void* d_ws, size_t ws_size,
                              hipStream_t stream) {
  const float* feat = (const float*)d_in[0];
  const float* protos = (const float*)d_in[1];
  const int* labels = (const int*)d_in[2];
  float* out = (float*)d_out;
  const int Bn = in_sizes[0] / 256;            // 262144 rows
  const int nblocks = Bn / 256;                // 1024 persistent-ish blocks
  unsigned short* pbf = (unsigned short*)d_ws; // 32 KB
  float* partials = (float*)((char*)d_ws + 64 * 256 * sizeof(unsigned short));

  hipLaunchKernelGGL(proto_prep, dim3(16), dim3(256), 0, stream, protos, pbf);
  hipLaunchKernelGGL(protonce_main, dim3(nblocks), dim3(256), 0, stream,
                     feat, pbf, labels, partials);
  hipLaunchKernelGGL(finalize_k, dim3(1), dim3(256), 0, stream, partials,
                     nblocks, out, 1.0f / (float)Bn);
}